// Round 1
// baseline (73.557 us; speedup 1.0000x reference)
//
#include <hip/hip_runtime.h>

// Problem constants (from reference setup_inputs)
#define B_DIM 8
#define F_DIM 16384
#define K_DIM 3
#define M_DIM 64

// SIGMA = 0.2 -> 1/(2*sigma^2) = 12.5 exactly
__device__ __constant__ float kInv2Sig2 = 12.5f;
#define LOG2E 1.4426950408889634f

// ws float layout: [0,64) sum, [64,128) sumsq, [128,192) A=gamma*invstd, [192,256) C=beta-mean*A

// ---------------------------------------------------------------------------
// Kernel A: compute feat[b,m,f] (pre-BN) into d_out, and accumulate per-m
// sum / sumsq partials into ws via wave-shuffle + LDS + global atomics.
// grid = 512 blocks (8 b * 64 f-chunks), block = 256
// ---------------------------------------------------------------------------
__global__ __launch_bounds__(256) void fkc_feat_kernel(
    const float* __restrict__ normals,   // [B,3,F]
    const float* __restrict__ walpha,    // [M*4]
    const float* __restrict__ wbeta,     // [M*4]
    const int*   __restrict__ nidx,      // [B,F,K] int32
    float* __restrict__ feat_out,        // [B,M,F] (d_out, pre-BN)
    float* __restrict__ ws)
{
    // packed kernel-point table: per (m,j): {wx,wy,wz,c} all pre-scaled
    __shared__ float4 sW[M_DIM * 4];
    __shared__ float sPartS[M_DIM][4];
    __shared__ float sPartQ[M_DIM][4];

    const int tid = threadIdx.x;

    // Build kernel-point table (256 threads -> 256 (m,j) entries)
    {
        float a = walpha[tid];
        float b = wbeta[tid];
        float sa = sinf(a), ca = cosf(a);
        float sb = sinf(b), cb = cosf(b);
        float wx = sa * cb, wy = sa * sb, wz = ca;
        float w2 = wx * wx + wy * wy + wz * wz;
        // arg(e-base) = 25*dot - 12.5*(p2 + w2); pre-scale by log2(e)
        const float s2 = 2.0f * kInv2Sig2 * LOG2E;   // 25*log2e
        const float s1 = -kInv2Sig2 * LOG2E;         // -12.5*log2e
        sW[tid] = make_float4(wx * s2, wy * s2, wz * s2, w2 * s1);
    }
    __syncthreads();

    const int b = blockIdx.x >> 6;                 // 64 blocks per batch
    const int f = ((blockIdx.x & 63) << 8) + tid;  // coalesced f

    const float* nb = normals + (size_t)b * 3 * F_DIM;
    float px[4], py[4], pz[4], pm[4];
    px[0] = nb[f];
    py[0] = nb[F_DIM + f];
    pz[0] = nb[2 * F_DIM + f];
    const int* ib = nidx + ((size_t)b * F_DIM + f) * K_DIM;
#pragma unroll
    for (int k = 0; k < K_DIM; ++k) {
        int id = ib[k];
        px[k + 1] = nb[id];
        py[k + 1] = nb[F_DIM + id];
        pz[k + 1] = nb[2 * F_DIM + id];
    }
    const float s1 = -kInv2Sig2 * LOG2E;
#pragma unroll
    for (int i = 0; i < 4; ++i)
        pm[i] = s1 * (px[i] * px[i] + py[i] * py[i] + pz[i] * pz[i]);

    const int wave = tid >> 6;
    const int lane = tid & 63;
    float* outb = feat_out + (size_t)b * M_DIM * F_DIM + f;

    for (int m = 0; m < M_DIM; ++m) {
        float s = 0.0f;
#pragma unroll
        for (int j = 0; j < 4; ++j) {
            float4 w = sW[m * 4 + j];
#pragma unroll
            for (int i = 0; i < 4; ++i) {
                float t = fmaf(w.x, px[i],
                          fmaf(w.y, py[i],
                          fmaf(w.z, pz[i], pm[i] + w.w)));
                s += __builtin_amdgcn_exp2f(t);
            }
        }
        float feat = s * (1.0f / 16.0f);
        outb[(size_t)m * F_DIM] = feat;

        // wave-level butterfly reduce of (feat, feat^2)
        float q = feat * feat;
        float rs = feat;
#pragma unroll
        for (int off = 32; off >= 1; off >>= 1) {
            rs += __shfl_xor(rs, off, 64);
            q  += __shfl_xor(q, off, 64);
        }
        if (lane == 0) {
            sPartS[m][wave] = rs;
            sPartQ[m][wave] = q;
        }
    }
    __syncthreads();

    if (tid < M_DIM) {
        float s4 = sPartS[tid][0] + sPartS[tid][1] + sPartS[tid][2] + sPartS[tid][3];
        float q4 = sPartQ[tid][0] + sPartQ[tid][1] + sPartQ[tid][2] + sPartQ[tid][3];
        atomicAdd(ws + tid, s4);
        atomicAdd(ws + M_DIM + tid, q4);
    }
}

// ---------------------------------------------------------------------------
// Kernel B: finalize per-channel scale/shift. 1 block x 64 threads.
// ---------------------------------------------------------------------------
__global__ void fkc_stats_kernel(const float* __restrict__ gamma,
                                 const float* __restrict__ beta,
                                 float* __restrict__ ws)
{
    int m = threadIdx.x;
    if (m < M_DIM) {
        const float invcnt = 1.0f / (float)(B_DIM * F_DIM);
        float mean = ws[m] * invcnt;
        float var  = ws[M_DIM + m] * invcnt - mean * mean;
        float inv  = rsqrtf(var + 1e-5f);
        float A = gamma[m] * inv;
        float C = beta[m] - mean * A;
        ws[2 * M_DIM + m] = A;
        ws[3 * M_DIM + m] = C;
    }
}

// ---------------------------------------------------------------------------
// Kernel C: in-place BN + ReLU over d_out, float4-vectorized.
// total float4 = B*M*F/4 = 2097152 ; grid = 8192 x 256
// ---------------------------------------------------------------------------
__global__ __launch_bounds__(256) void fkc_bn_kernel(float* __restrict__ out,
                                                     const float* __restrict__ ws)
{
    size_t i4 = (size_t)blockIdx.x * blockDim.x + threadIdx.x;
    int m = (int)((i4 >> 12) & 63);   // (i4*4 / F) % M, F=16384
    float A = ws[2 * M_DIM + m];
    float C = ws[3 * M_DIM + m];
    float4 v = reinterpret_cast<float4*>(out)[i4];
    v.x = fmaxf(fmaf(v.x, A, C), 0.0f);
    v.y = fmaxf(fmaf(v.y, A, C), 0.0f);
    v.z = fmaxf(fmaf(v.z, A, C), 0.0f);
    v.w = fmaxf(fmaf(v.w, A, C), 0.0f);
    reinterpret_cast<float4*>(out)[i4] = v;
}

// ---------------------------------------------------------------------------
extern "C" void kernel_launch(void* const* d_in, const int* in_sizes, int n_in,
                              void* d_out, int out_size, void* d_ws, size_t ws_size,
                              hipStream_t stream)
{
    const float* normals = (const float*)d_in[0];
    const float* walpha  = (const float*)d_in[1];
    const float* wbeta   = (const float*)d_in[2];
    const float* gamma   = (const float*)d_in[3];
    const float* beta    = (const float*)d_in[4];
    const int*   nidx    = (const int*)d_in[5];
    float* out = (float*)d_out;
    float* ws  = (float*)d_ws;

    // zero the per-m accumulators every launch (harness does not re-poison)
    hipMemsetAsync(ws, 0, 2 * M_DIM * sizeof(float), stream);

    hipLaunchKernelGGL(fkc_feat_kernel, dim3(512), dim3(256), 0, stream,
                       normals, walpha, wbeta, nidx, out, ws);
    hipLaunchKernelGGL(fkc_stats_kernel, dim3(1), dim3(64), 0, stream,
                       gamma, beta, ws);
    hipLaunchKernelGGL(fkc_bn_kernel, dim3(8192), dim3(256), 0, stream,
                       out, ws);
}

// Round 2
// 62.329 us; speedup vs baseline: 1.1801x; 1.1801x over previous
//
#include <hip/hip_runtime.h>

// Problem constants (from reference setup_inputs)
#define B_DIM 8
#define F_DIM 16384
#define K_DIM 3
#define M_DIM 64
#define MCH   16                     // m-values per block in feat kernel
#define LOG2E 1.4426950408889634f

// ws float layout: [0,64) sum, [64,128) sumsq, [128,192) A=gamma*invstd, [192,256) C=beta-mean*A

// ---------------------------------------------------------------------------
// Kernel A: feat[b,m,f] (pre-BN) into d_out. Pure compute, no reductions.
// grid = 2048 (8 b * 4 mchunk * 64 fchunk), block = 256
// ---------------------------------------------------------------------------
__global__ __launch_bounds__(256) void fkc_feat_kernel(
    const float* __restrict__ normals,   // [B,3,F]
    const float* __restrict__ walpha,    // [M*4]
    const float* __restrict__ wbeta,     // [M*4]
    const int*   __restrict__ nidx,      // [B,F,K] int32
    float* __restrict__ feat_out)        // [B,M,F]
{
    __shared__ float4 sW[MCH * 4];
    const int tid = threadIdx.x;
    const int b  = blockIdx.x >> 8;          // 256 blocks per batch
    const int mc = (blockIdx.x >> 6) & 3;    // m-chunk
    const int fc = blockIdx.x & 63;          // f-chunk

    // Build this block's 64-entry kernel-point table.
    // ||p||^2 == 1 (unit normals), folded into the .w term:
    // arg_log2 = 25*log2e*dot - 12.5*log2e*(1 + ||w||^2)
    if (tid < MCH * 4) {
        int idx = mc * MCH * 4 + tid;        // flat (m,j)
        float a = walpha[idx], bb = wbeta[idx];
        float sa = sinf(a), ca = cosf(a);
        float sb = sinf(bb), cb = cosf(bb);
        float wx = sa * cb, wy = sa * sb, wz = ca;
        float w2 = wx * wx + wy * wy + wz * wz;
        const float s2 = 25.0f * LOG2E;
        const float s1 = -12.5f * LOG2E;
        sW[tid] = make_float4(wx * s2, wy * s2, wz * s2, s1 * (w2 + 1.0f));
    }
    __syncthreads();

    const int f = (fc << 8) + tid;           // coalesced f
    const float* nb = normals + (size_t)b * 3 * F_DIM;
    float px[4], py[4], pz[4];
    px[0] = nb[f];
    py[0] = nb[F_DIM + f];
    pz[0] = nb[2 * F_DIM + f];
    const int* ib = nidx + ((size_t)b * F_DIM + f) * K_DIM;
#pragma unroll
    for (int k = 0; k < K_DIM; ++k) {
        int id = ib[k];
        px[k + 1] = nb[id];
        py[k + 1] = nb[F_DIM + id];
        pz[k + 1] = nb[2 * F_DIM + id];
    }

    float* outb = feat_out + ((size_t)b * M_DIM + mc * MCH) * F_DIM + f;
#pragma unroll 2
    for (int m = 0; m < MCH; ++m) {
        // 4 independent accumulators (one per point) to break the add chain
        float s0 = 0.f, s1 = 0.f, s2 = 0.f, s3 = 0.f;
#pragma unroll
        for (int j = 0; j < 4; ++j) {
            float4 w = sW[m * 4 + j];
            s0 += __builtin_amdgcn_exp2f(fmaf(w.x, px[0], fmaf(w.y, py[0], fmaf(w.z, pz[0], w.w))));
            s1 += __builtin_amdgcn_exp2f(fmaf(w.x, px[1], fmaf(w.y, py[1], fmaf(w.z, pz[1], w.w))));
            s2 += __builtin_amdgcn_exp2f(fmaf(w.x, px[2], fmaf(w.y, py[2], fmaf(w.z, pz[2], w.w))));
            s3 += __builtin_amdgcn_exp2f(fmaf(w.x, px[3], fmaf(w.y, py[3], fmaf(w.z, pz[3], w.w))));
        }
        outb[(size_t)m * F_DIM] = ((s0 + s1) + (s2 + s3)) * (1.0f / 16.0f);
    }
}

// ---------------------------------------------------------------------------
// Kernel B: per-channel sum/sumsq over feat (memory-bound, L3-resident).
// grid = B*M = 512 blocks, one (b,m) row of 16384 floats each.
// ---------------------------------------------------------------------------
__global__ __launch_bounds__(256) void fkc_sum_kernel(const float* __restrict__ feat,
                                                      float* __restrict__ ws)
{
    __shared__ float sS[4], sQ[4];
    const int row = blockIdx.x;              // b*64 + m
    const int m = row & 63;
    const int tid = threadIdx.x;
    const float4* p4 = (const float4*)(feat + (size_t)row * F_DIM);

    float s = 0.f, q = 0.f;
#pragma unroll
    for (int i = 0; i < 16; ++i) {           // 4096 float4 / 256 threads
        float4 v = p4[tid + i * 256];
        s += (v.x + v.y) + (v.z + v.w);
        q += (v.x * v.x + v.y * v.y) + (v.z * v.z + v.w * v.w);
    }
#pragma unroll
    for (int off = 32; off >= 1; off >>= 1) {
        s += __shfl_xor(s, off, 64);
        q += __shfl_xor(q, off, 64);
    }
    const int wave = tid >> 6, lane = tid & 63;
    if (lane == 0) { sS[wave] = s; sQ[wave] = q; }
    __syncthreads();
    if (tid == 0) {
        atomicAdd(ws + m,         (sS[0] + sS[1]) + (sS[2] + sS[3]));
        atomicAdd(ws + M_DIM + m, (sQ[0] + sQ[1]) + (sQ[2] + sQ[3]));
    }
}

// ---------------------------------------------------------------------------
// Kernel C: finalize per-channel scale/shift. 1 block x 64 threads.
// ---------------------------------------------------------------------------
__global__ void fkc_stats_kernel(const float* __restrict__ gamma,
                                 const float* __restrict__ beta,
                                 float* __restrict__ ws)
{
    int m = threadIdx.x;
    if (m < M_DIM) {
        const float invcnt = 1.0f / (float)(B_DIM * F_DIM);
        float mean = ws[m] * invcnt;
        float var  = ws[M_DIM + m] * invcnt - mean * mean;
        float inv  = rsqrtf(var + 1e-5f);
        float A = gamma[m] * inv;
        float C = beta[m] - mean * A;
        ws[2 * M_DIM + m] = A;
        ws[3 * M_DIM + m] = C;
    }
}

// ---------------------------------------------------------------------------
// Kernel D: in-place BN + ReLU over d_out, float4-vectorized.
// ---------------------------------------------------------------------------
__global__ __launch_bounds__(256) void fkc_bn_kernel(float* __restrict__ out,
                                                     const float* __restrict__ ws)
{
    size_t i4 = (size_t)blockIdx.x * blockDim.x + threadIdx.x;
    int m = (int)((i4 >> 12) & 63);          // (i4*4 / F) % M, F=16384
    float A = ws[2 * M_DIM + m];
    float C = ws[3 * M_DIM + m];
    float4 v = reinterpret_cast<float4*>(out)[i4];
    v.x = fmaxf(fmaf(v.x, A, C), 0.0f);
    v.y = fmaxf(fmaf(v.y, A, C), 0.0f);
    v.z = fmaxf(fmaf(v.z, A, C), 0.0f);
    v.w = fmaxf(fmaf(v.w, A, C), 0.0f);
    reinterpret_cast<float4*>(out)[i4] = v;
}

// ---------------------------------------------------------------------------
extern "C" void kernel_launch(void* const* d_in, const int* in_sizes, int n_in,
                              void* d_out, int out_size, void* d_ws, size_t ws_size,
                              hipStream_t stream)
{
    const float* normals = (const float*)d_in[0];
    const float* walpha  = (const float*)d_in[1];
    const float* wbeta   = (const float*)d_in[2];
    const float* gamma   = (const float*)d_in[3];
    const float* beta    = (const float*)d_in[4];
    const int*   nidx    = (const int*)d_in[5];
    float* out = (float*)d_out;
    float* ws  = (float*)d_ws;

    // zero the per-m accumulators every launch (harness does not re-poison)
    hipMemsetAsync(ws, 0, 2 * M_DIM * sizeof(float), stream);

    hipLaunchKernelGGL(fkc_feat_kernel, dim3(2048), dim3(256), 0, stream,
                       normals, walpha, wbeta, nidx, out);
    hipLaunchKernelGGL(fkc_sum_kernel, dim3(B_DIM * M_DIM), dim3(256), 0, stream,
                       out, ws);
    hipLaunchKernelGGL(fkc_stats_kernel, dim3(1), dim3(64), 0, stream,
                       gamma, beta, ws);
    hipLaunchKernelGGL(fkc_bn_kernel, dim3(8192), dim3(256), 0, stream,
                       out, ws);
}